// Round 5
// baseline (517.383 us; speedup 1.0000x reference)
//
#include <hip/hip_runtime.h>
#include <math.h>

typedef float f4 __attribute__((ext_vector_type(4)));
typedef _Float16 half8 __attribute__((ext_vector_type(8)));

#define C_DIM 256
#define NH 8
#define HD 32
#define Q_DIM 1000
#define N_PTS 16
#define B_DIM 16
#define H_IMG 100
#define W_IMG 100
#define HW 10000
#define BQ2 2
#define NS 32
#define N_QK 2048   // NH * C_DIM

// ===========================================================================
// NEW PATH (f16 + MFMA)
// ===========================================================================

// ---- x [B,C,HW] f32 -> xt [B,HW,C] f16 ------------------------------------
__global__ __launch_bounds__(256) void xt_kernel(
    const float* __restrict__ x, _Float16* __restrict__ xt) {
  __shared__ float t[64][65];
  int p0 = blockIdx.x * 64;
  int c0 = blockIdx.y * 64;
  int b = blockIdx.z;
  int tid = threadIdx.x;
  int p4 = tid & 15, cl = tid >> 4;
#pragma unroll
  for (int it = 0; it < 4; ++it) {
    int c = cl + 16 * it;
    int p = p0 + p4 * 4;
    f4 v = {0.f, 0.f, 0.f, 0.f};
    const float* sp = x + ((size_t)b * C_DIM + c0 + c) * HW;
    if (p + 3 < HW) {
      v = *(const f4*)(sp + p);
    } else {
#pragma unroll
      for (int j = 0; j < 4; ++j) if (p + j < HW) v[j] = sp[p + j];
    }
    t[p4 * 4 + 0][c] = v[0];
    t[p4 * 4 + 1][c] = v[1];
    t[p4 * 4 + 2][c] = v[2];
    t[p4 * 4 + 3][c] = v[3];
  }
  __syncthreads();
  int pl = tid >> 2, cq = tid & 3;
  int p = p0 + pl;
  if (p < HW) {
    half8 h0, h1;
#pragma unroll
    for (int j = 0; j < 8; ++j) {
      h0[j] = (_Float16)t[pl][cq * 16 + j];
      h1[j] = (_Float16)t[pl][cq * 16 + 8 + j];
    }
    _Float16* dst = xt + ((size_t)b * HW + p) * C_DIM + c0 + cq * 16;
    *(half8*)dst = h0;
    *(half8*)(dst + 8) = h1;
  }
}

// ---- q f32 -> f16 ---------------------------------------------------------
__global__ __launch_bounds__(256) void qconv_kernel(
    const float* __restrict__ q, _Float16* __restrict__ qh) {
  size_t i = ((size_t)blockIdx.x * 256 + threadIdx.x) * 8;
  f4 v0 = *(const f4*)(q + i);
  f4 v1 = *(const f4*)(q + i + 4);
  half8 h;
  h[0] = (_Float16)v0[0]; h[1] = (_Float16)v0[1];
  h[2] = (_Float16)v0[2]; h[3] = (_Float16)v0[3];
  h[4] = (_Float16)v1[0]; h[5] = (_Float16)v1[1];
  h[6] = (_Float16)v1[2]; h[7] = (_Float16)v1[3];
  *(half8*)(qh + i) = h;
}

// ---- wqkB[n][c] f16 = s * sum_dd wq[h*HD+dd][c] * wk[h*HD+dd][cp] ---------
__global__ __launch_bounds__(256) void prep_wqk(
    const float* __restrict__ wq, const float* __restrict__ wk,
    const float* __restrict__ bq, _Float16* __restrict__ wqkB,
    float* __restrict__ qkb) {
  int n = blockIdx.x;
  int h = n >> 8, cp = n & 255;
  int c = threadIdx.x;
  float acc = 0.f, accb = 0.f;
#pragma unroll 4
  for (int dd = 0; dd < HD; ++dd) {
    float wkv = wk[(size_t)(h * HD + dd) * C_DIM + cp];
    acc += wq[(size_t)(h * HD + dd) * C_DIM + c] * wkv;
    accb += bq[h * HD + dd] * wkv;
  }
  const float s = 0.17677669529663687f;  // 1/sqrt(32)
  wqkB[(size_t)n * C_DIM + c] = (_Float16)(acc * s);
  if (c == 0) qkb[n] = accb * s;
}

// ---- wv f32 -> f16 --------------------------------------------------------
__global__ __launch_bounds__(256) void prep_wv(
    const float* __restrict__ wv, _Float16* __restrict__ wvh) {
  int i = blockIdx.x * 256 + threadIdx.x;
  wvh[i] = (_Float16)wv[i];
}

// ---- qk_g[m][n] f16 = qh[m][k] @ wqkB[n][k]^T + qkb[n]  (tiled MFMA) ------
__global__ __launch_bounds__(256) void qk_gemm(
    const _Float16* __restrict__ qh, const _Float16* __restrict__ wqkB,
    const float* __restrict__ qkb, _Float16* __restrict__ qk_g) {
  __shared__ __align__(16) _Float16 lds_buf[2 * 128 * 72];
  _Float16* As = lds_buf;
  _Float16* Bs = lds_buf + 128 * 72;

  int tid = threadIdx.x;
  int m0 = blockIdx.x * 128;
  int n0 = blockIdx.y * 128;
  int wid = tid >> 6, lane = tid & 63;
  int wm = wid >> 1, wn = wid & 1;
  int m_ = lane & 15, kq = lane >> 4;

  f4 acc[4][4];
#pragma unroll
  for (int i = 0; i < 4; ++i)
#pragma unroll
    for (int j = 0; j < 4; ++j) acc[i][j] = {0.f, 0.f, 0.f, 0.f};

#pragma unroll 1
  for (int k0 = 0; k0 < C_DIM; k0 += 64) {
    if (k0) __syncthreads();
#pragma unroll
    for (int j = 0; j < 4; ++j) {
      int idx = j * 256 + tid;
      int r = idx >> 3, kc = idx & 7;
      *(half8*)&As[r * 72 + kc * 8] =
          *(const half8*)(qh + (size_t)(m0 + r) * C_DIM + k0 + kc * 8);
      *(half8*)&Bs[r * 72 + kc * 8] =
          *(const half8*)(wqkB + (size_t)(n0 + r) * C_DIM + k0 + kc * 8);
    }
    __syncthreads();
#pragma unroll
    for (int kk = 0; kk < 64; kk += 32) {
      half8 af[4], bf[4];
#pragma unroll
      for (int mt = 0; mt < 4; ++mt)
        af[mt] = *(const half8*)&As[(wm * 64 + mt * 16 + m_) * 72 + kk + kq * 8];
#pragma unroll
      for (int nt = 0; nt < 4; ++nt)
        bf[nt] = *(const half8*)&Bs[(wn * 64 + nt * 16 + m_) * 72 + kk + kq * 8];
#pragma unroll
      for (int mt = 0; mt < 4; ++mt)
#pragma unroll
        for (int nt = 0; nt < 4; ++nt)
          acc[mt][nt] = __builtin_amdgcn_mfma_f32_16x16x32_f16(
              af[mt], bf[nt], acc[mt][nt], 0, 0, 0);
    }
  }

  __syncthreads();
  _Float16* Cs = lds_buf;  // [128][136]
#pragma unroll
  for (int nt = 0; nt < 4; ++nt) {
    int col_l = wn * 64 + nt * 16 + m_;
    float qb = qkb[n0 + col_l];
#pragma unroll
    for (int mt = 0; mt < 4; ++mt) {
      int row_b = wm * 64 + mt * 16 + kq * 4;
#pragma unroll
      for (int r = 0; r < 4; ++r)
        Cs[(row_b + r) * 136 + col_l] = (_Float16)(acc[mt][nt][r] + qb);
    }
  }
  __syncthreads();
#pragma unroll
  for (int j = 0; j < 8; ++j) {
    int idx = j * 256 + tid;
    int r = idx >> 4, cc = idx & 15;
    *(half8*)(qk_g + (size_t)(m0 + r) * N_QK + n0 + cc * 8) =
        *(const half8*)&Cs[r * 136 + cc * 8];
  }
}

// ---- fused gather + logits(MFMA) + softmax + pv + output proj (MFMA) ------
__global__ __launch_bounds__(256) void attn_mfma_kernel(
    const _Float16* __restrict__ xt, const float* __restrict__ ref,
    const _Float16* __restrict__ qk_g, const _Float16* __restrict__ wvh,
    const float* __restrict__ bv, float* __restrict__ out) {
  __shared__ __align__(16) _Float16 samp[NS][264];
  __shared__ __align__(16) _Float16 qks[16][264];   // qk, then pv
  __shared__ float p_s[16][36];

  int tid = threadIdx.x;
  int q2g = blockIdx.x;
  int b = blockIdx.y;
  int q2_0 = q2g * BQ2;
  int m0 = q2g * NS;
  int wid = tid >> 6, lane = tid & 63;
  int m_ = lane & 15, kq = lane >> 4;

  // stage qk rows: pair = q2l*8+h
  {
    int pair = tid >> 4;
    int col = (tid & 15) * 16;
    int qq = q2_0 + (pair >> 3);
    int hh = pair & 7;
    const _Float16* src = qk_g + ((size_t)b * Q_DIM + qq) * N_QK + hh * C_DIM + col;
    *(half8*)&qks[pair][col] = *(const half8*)src;
    *(half8*)&qks[pair][col + 8] = *(const half8*)(src + 8);
  }

  // gather: half-wave per sample, packed f16 weighting
  {
    int s_half = tid >> 5, cl = tid & 31;
    const _Float16* base = xt + (size_t)b * HW * C_DIM + cl * 8;
#pragma unroll 1
    for (int it = 0; it < 4; ++it) {
      int i = it * 8 + s_half;
      int mm = m0 + i;
      int qq = mm % Q_DIM, nn = mm / Q_DIM;
      const float* rp = ref + (((size_t)b * Q_DIM + qq) * N_PTS + nn) * 2;
      float gx = (rp[0] + 1.f) * 50.f - 0.5f;
      float gy = (rp[1] + 1.f) * 50.f - 0.5f;
      float fx0 = floorf(gx), fy0 = floorf(gy);
      float fx = gx - fx0, fy = gy - fy0;
      int ix0 = (int)fx0, iy0 = (int)fy0;
      int ix1 = ix0 + 1, iy1 = iy0 + 1;
      bool x0ok = ix0 >= 0 && ix0 < W_IMG, x1ok = ix1 >= 0 && ix1 < W_IMG;
      bool y0ok = iy0 >= 0 && iy0 < H_IMG, y1ok = iy1 >= 0 && iy1 < H_IMG;
      half8 acc = {0, 0, 0, 0, 0, 0, 0, 0};
      if (x0ok && y0ok) {
        half8 v = *(const half8*)(base + (size_t)(iy0 * W_IMG + ix0) * C_DIM);
        acc += v * (_Float16)((1.f - fx) * (1.f - fy));
      }
      if (x1ok && y0ok) {
        half8 v = *(const half8*)(base + (size_t)(iy0 * W_IMG + ix1) * C_DIM);
        acc += v * (_Float16)(fx * (1.f - fy));
      }
      if (x0ok && y1ok) {
        half8 v = *(const half8*)(base + (size_t)(iy1 * W_IMG + ix0) * C_DIM);
        acc += v * (_Float16)((1.f - fx) * fy);
      }
      if (x1ok && y1ok) {
        half8 v = *(const half8*)(base + (size_t)(iy1 * W_IMG + ix1) * C_DIM);
        acc += v * (_Float16)(fx * fy);
      }
      *(half8*)&samp[i][cl * 8] = acc;
    }
  }
  __syncthreads();

  // logits via MFMA on waves 0,1 then softmax via shfl
  if (wid < 2) {
    f4 d = {0.f, 0.f, 0.f, 0.f};
#pragma unroll
    for (int ks = 0; ks < 8; ++ks) {
      half8 a = *(const half8*)&qks[m_][ks * 32 + kq * 8];
      half8 bfr = *(const half8*)&samp[wid * 16 + m_][ks * 32 + kq * 8];
      d = __builtin_amdgcn_mfma_f32_16x16x32_f16(a, bfr, d, 0, 0, 0);
    }
#pragma unroll
    for (int r = 0; r < 4; ++r) {
      int pair = kq * 4 + r;
      float v = d[r];
      float mx = v;
#pragma unroll
      for (int off = 1; off < 16; off <<= 1) mx = fmaxf(mx, __shfl_xor(mx, off, 16));
      float e = __expf(v - mx);
      float s = e;
#pragma unroll
      for (int off = 1; off < 16; off <<= 1) s += __shfl_xor(s, off, 16);
      if ((pair >> 3) == wid) p_s[pair][wid * 16 + m_] = e / s;
    }
  }
  __syncthreads();

  // pv[pair][c'] = sum_n p * samp  (packed f16, 2 accumulators) -> qks
  {
    int chunk = tid & 31, pg = tid >> 5;  // pg = head
    half8 aA0 = {0,0,0,0,0,0,0,0}, aA1 = aA0, aB0 = aA0, aB1 = aA0;
#pragma unroll
    for (int n = 0; n < 16; n += 2) {
      half8 s0a = *(const half8*)&samp[n][chunk * 8];
      half8 s0b = *(const half8*)&samp[n + 1][chunk * 8];
      half8 s1a = *(const half8*)&samp[16 + n][chunk * 8];
      half8 s1b = *(const half8*)&samp[17 + n][chunk * 8];
      aA0 += s0a * (_Float16)p_s[pg][n];
      aA1 += s0b * (_Float16)p_s[pg][n + 1];
      aB0 += s1a * (_Float16)p_s[pg + 8][16 + n];
      aB1 += s1b * (_Float16)p_s[pg + 8][17 + n];
    }
    half8 oA = aA0 + aA1;
    half8 oB = aB0 + aB1;
    __syncthreads();  // all logits-reads of qks complete
    *(half8*)&qks[pg][chunk * 8] = oA;       // pair = 0*8+pg (query 0)
    *(half8*)&qks[8 + pg][chunk * 8] = oB;   // pair = 1*8+pg (query 1)
  }
  __syncthreads();

  // output proj: per-wave MFMA, A = pv rows (LDS), B = wvh rows (global)
  {
    half8 af[8];
#pragma unroll
    for (int ks = 0; ks < 8; ++ks)
      af[ks] = *(const half8*)&qks[m_][ks * 32 + kq * 8];
#pragma unroll
    for (int hh = 0; hh < 2; ++hh) {
      int h = wid * 2 + hh;
#pragma unroll
      for (int nt = 0; nt < 2; ++nt) {
        int c = h * 32 + nt * 16 + m_;
        const _Float16* brow = wvh + (size_t)c * C_DIM + kq * 8;
        f4 acc = {0.f, 0.f, 0.f, 0.f};
#pragma unroll
        for (int ks = 0; ks < 8; ++ks)
          acc = __builtin_amdgcn_mfma_f32_16x16x32_f16(
              af[ks], *(const half8*)(brow + ks * 32), acc, 0, 0, 0);
        float bvv = bv[c];
#pragma unroll
        for (int r = 0; r < 4; ++r) {
          int row = kq * 4 + r;
          if (row == h)
            out[((size_t)b * Q_DIM + q2_0) * C_DIM + c] = acc[r] + bvv;
          if (row == h + 8)
            out[((size_t)b * Q_DIM + q2_0 + 1) * C_DIM + c] = acc[r] + bvv;
        }
      }
    }
  }
}

// ===========================================================================
// FALLBACK PATH (fp32, used only if workspace is too small)
// ===========================================================================
__global__ __launch_bounds__(256) void transpose_kernel(
    const float* __restrict__ in, float* __restrict__ out, int rows, int cols) {
  __shared__ float t[32][33];
  size_t off = (size_t)blockIdx.z * rows * cols;
  int r0 = blockIdx.y * 32, c0 = blockIdx.x * 32;
  int tx = threadIdx.x, ty = threadIdx.y;
#pragma unroll
  for (int k = 0; k < 4; ++k) {
    int r = r0 + ty + 8 * k, c = c0 + tx;
    if (r < rows && c < cols) t[ty + 8 * k][tx] = in[off + (size_t)r * cols + c];
  }
  __syncthreads();
#pragma unroll
  for (int k = 0; k < 4; ++k) {
    int c = c0 + ty + 8 * k, r = r0 + tx;
    if (r < rows && c < cols) out[off + (size_t)c * rows + r] = t[tx][ty + 8 * k];
  }
}

__global__ __launch_bounds__(256) void qp_kernel(
    const float* __restrict__ q, const float* __restrict__ wq,
    const float* __restrict__ bq, float* __restrict__ qp) {
  __shared__ float qrows[16][257];
  int row0 = blockIdx.x * 16;
  int tid = threadIdx.x;
  for (int t = tid; t < 16 * C_DIM; t += 256) {
    int r = t >> 8, c = t & 255;
    qrows[r][c] = q[(size_t)(row0 + r) * C_DIM + c];
  }
  __syncthreads();
  float acc[16];
  float b0 = bq[tid];
#pragma unroll
  for (int r = 0; r < 16; ++r) acc[r] = b0;
  const float* wrow = wq + (size_t)tid * C_DIM;
  for (int cc = 0; cc < C_DIM; ++cc) {
    float w = wrow[cc];
#pragma unroll
    for (int r = 0; r < 16; ++r) acc[r] += qrows[r][cc] * w;
  }
#pragma unroll
  for (int r = 0; r < 16; ++r) qp[(size_t)(row0 + r) * C_DIM + tid] = acc[r];
}

__global__ __launch_bounds__(256) void attn_fb_kernel(
    const float* __restrict__ src, int strB, int strY, int strX, int strC,
    const float* __restrict__ ref, const float* __restrict__ qp,
    const float* __restrict__ q, const float* __restrict__ wq,
    const float* __restrict__ bq, const float* __restrict__ wk,
    const float* __restrict__ wv, const float* __restrict__ bv,
    float* __restrict__ out) {
  __shared__ __align__(16) float qp_s[BQ2][C_DIM];
  __shared__ __align__(16) float qk_s[16][260];
  __shared__ __align__(16) float samp_f[NS][260];
  __shared__ float p_f[16][16];
  __shared__ float logit_s[256];

  int tid = threadIdx.x;
  int q2g = blockIdx.x;
  int b = blockIdx.y;
  int q2_0 = q2g * BQ2;
  int m0 = q2g * NS;
  int c4 = tid & 63;
  int grp = tid >> 6;

  if (qp) {
    if (tid < 128) {
      int r = tid >> 6, cc4 = tid & 63;
      *(f4*)&qp_s[r][cc4 * 4] =
          *(const f4*)(qp + ((size_t)b * Q_DIM + q2_0 + r) * C_DIM + cc4 * 4);
    }
  } else {
#pragma unroll
    for (int r = 0; r < BQ2; ++r) {
      float acc = bq[tid];
      const float* qrow = q + ((size_t)b * Q_DIM + q2_0 + r) * C_DIM;
      const float* wrow = wq + (size_t)tid * C_DIM;
      for (int cc = 0; cc < C_DIM; ++cc) acc += qrow[cc] * wrow[cc];
      qp_s[r][tid] = acc;
    }
  }

  {
    int coff = tid * strC;
#pragma unroll 1
    for (int i = 0; i < NS; ++i) {
      int mm = m0 + i;
      int qq = mm % Q_DIM;
      int nn = mm / Q_DIM;
      const float* rp = ref + (((size_t)b * Q_DIM + qq) * N_PTS + nn) * 2;
      float gx = (rp[0] + 1.f) * 50.f - 0.5f;
      float gy = (rp[1] + 1.f) * 50.f - 0.5f;
      float fx0 = floorf(gx), fy0 = floorf(gy);
      float fx = gx - fx0, fy = gy - fy0;
      int ix0 = (int)fx0, iy0 = (int)fy0;
      int ix1 = ix0 + 1, iy1 = iy0 + 1;
      float w00 = (1.f - fx) * (1.f - fy);
      float w01 = fx * (1.f - fy);
      float w10 = (1.f - fx) * fy;
      float w11 = fx * fy;
      size_t bse = (size_t)(b * strB + coff);
      float v = 0.f;
      if (ix0 >= 0 && ix0 < W_IMG) {
        if (iy0 >= 0 && iy0 < H_IMG) v += w00 * src[bse + (size_t)iy0 * strY + (size_t)ix0 * strX];
        if (iy1 >= 0 && iy1 < H_IMG) v += w10 * src[bse + (size_t)iy1 * strY + (size_t)ix0 * strX];
      }
      if (ix1 >= 0 && ix1 < W_IMG) {
        if (iy0 >= 0 && iy0 < H_IMG) v += w01 * src[bse + (size_t)iy0 * strY + (size_t)ix1 * strX];
        if (iy1 >= 0 && iy1 < H_IMG) v += w11 * src[bse + (size_t)iy1 * strY + (size_t)ix1 * strX];
      }
      samp_f[i][tid] = v;
    }
  }
  __syncthreads();

#pragma unroll 1
  for (int hh = 0; hh < 2; ++hh) {
    int h = grp * 2 + hh;
    f4 acc0 = {0.f, 0.f, 0.f, 0.f};
    f4 acc1 = {0.f, 0.f, 0.f, 0.f};
#pragma unroll 2
    for (int dd4 = 0; dd4 < 8; ++dd4) {
      f4 a0 = *(const f4*)&qp_s[0][h * HD + dd4 * 4];
      f4 a1 = *(const f4*)&qp_s[1][h * HD + dd4 * 4];
#pragma unroll
      for (int j = 0; j < 4; ++j) {
        f4 w4 = *(const f4*)(wk + (size_t)(h * HD + dd4 * 4 + j) * C_DIM + c4 * 4);
        acc0 += a0[j] * w4;
        acc1 += a1[j] * w4;
      }
    }
    *(f4*)&qk_s[h][c4 * 4] = acc0;
    *(f4*)&qk_s[8 + h][c4 * 4] = acc1;
  }
  __syncthreads();

  {
    int pair = tid >> 4;
    int n2 = tid & 15;
    int i = (pair >> 3) * 16 + n2;
    float acc = 0.f;
#pragma unroll 4
    for (int cc4 = 0; cc4 < 64; ++cc4) {
      f4 qk4 = *(const f4*)&qk_s[pair][cc4 * 4];
      f4 s4 = *(const f4*)&samp_f[i][cc4 * 4];
      acc += qk4[0] * s4[0] + qk4[1] * s4[1] + qk4[2] * s4[2] + qk4[3] * s4[3];
    }
    logit_s[tid] = acc * 0.17677669529663687f;
  }
  __syncthreads();

  if (tid < 16) {
    float mx = -1e30f;
#pragma unroll
    for (int n2 = 0; n2 < 16; ++n2) mx = fmaxf(mx, logit_s[tid * 16 + n2]);
    float s = 0.f;
    float e[16];
#pragma unroll
    for (int n2 = 0; n2 < 16; ++n2) {
      e[n2] = __expf(logit_s[tid * 16 + n2] - mx);
      s += e[n2];
    }
    float inv = 1.f / s;
#pragma unroll
    for (int n2 = 0; n2 < 16; ++n2) p_f[tid][n2] = e[n2] * inv;
  }
  __syncthreads();

#pragma unroll 1
  for (int k = 0; k < 4; ++k) {
    int pair = k * 4 + grp;
    int roff = (pair >> 3) * 16;
    f4 acc = {0.f, 0.f, 0.f, 0.f};
#pragma unroll
    for (int n2 = 0; n2 < 16; ++n2)
      acc += p_f[pair][n2] * *(const f4*)&samp_f[roff + n2][c4 * 4];
    *(f4*)&qk_s[pair][c4 * 4] = acc;
  }
  __syncthreads();

  {
    int h = tid >> 5;
    float acc0 = 0.f, acc1 = 0.f;
#pragma unroll 4
    for (int cc4 = 0; cc4 < 64; ++cc4) {
      f4 pv0 = *(const f4*)&qk_s[h][cc4 * 4];
      f4 pv1 = *(const f4*)&qk_s[8 + h][cc4 * 4];
      f4 w4 = *(const f4*)(wv + (size_t)tid * C_DIM + cc4 * 4);
      acc0 += pv0[0] * w4[0] + pv0[1] * w4[1] + pv0[2] * w4[2] + pv0[3] * w4[3];
      acc1 += pv1[0] * w4[0] + pv1[1] * w4[1] + pv1[2] * w4[2] + pv1[3] * w4[3];
    }
    float bvv = bv[tid];
    out[((size_t)b * Q_DIM + q2_0) * C_DIM + tid] = acc0 + bvv;
    out[((size_t)b * Q_DIM + q2_0 + 1) * C_DIM + tid] = acc1 + bvv;
  }
}

// ===========================================================================
extern "C" void kernel_launch(void* const* d_in, const int* in_sizes, int n_in,
                              void* d_out, int out_size, void* d_ws, size_t ws_size,
                              hipStream_t stream) {
  const float* x   = (const float*)d_in[0];
  const float* q   = (const float*)d_in[1];
  const float* ref = (const float*)d_in[2];
  const float* wq  = (const float*)d_in[3];
  const float* bq  = (const float*)d_in[4];
  const float* wk  = (const float*)d_in[5];
  // d_in[6] = bk: cancels in softmax (constant shift per row)
  const float* wv  = (const float*)d_in[7];
  const float* bv  = (const float*)d_in[8];
  float* out = (float*)d_out;

  const size_t XT_B    = (size_t)B_DIM * HW * C_DIM * 2;          // 81.92 MB
  const size_t QK_B    = (size_t)B_DIM * Q_DIM * N_QK * 2;        // 65.5 MB
  const size_t QH_B    = (size_t)B_DIM * Q_DIM * C_DIM * 2;       // 8.2 MB
  const size_t WQKB_B  = (size_t)N_QK * C_DIM * 2;                // 1 MB
  const size_t QKB_B   = (size_t)N_QK * 4;                        // 8 KB
  const size_t WVH_B   = (size_t)C_DIM * C_DIM * 2;               // 128 KB
  const size_t NEED    = XT_B + QK_B + QH_B + WQKB_B + QKB_B + WVH_B;

  if (ws_size >= NEED) {
    char* p = (char*)d_ws;
    _Float16* xt    = (_Float16*)p;           p += XT_B;
    _Float16* qk_g  = (_Float16*)p;           p += QK_B;
    _Float16* qh    = (_Float16*)p;           p += QH_B;
    _Float16* wqkB  = (_Float16*)p;           p += WQKB_B;
    float*    qkb   = (float*)p;              p += QKB_B;
    _Float16* wvh   = (_Float16*)p;

    xt_kernel<<<dim3((HW + 63) / 64, C_DIM / 64, B_DIM), 256, 0, stream>>>(x, xt);
    qconv_kernel<<<(B_DIM * Q_DIM * C_DIM) / (256 * 8), 256, 0, stream>>>(q, qh);
    prep_wqk<<<N_QK, 256, 0, stream>>>(wq, wk, bq, wqkB, qkb);
    prep_wv<<<C_DIM * C_DIM / 256, 256, 0, stream>>>(wv, wvh);
    qk_gemm<<<dim3(B_DIM * Q_DIM / 128, N_QK / 128), 256, 0, stream>>>(qh, wqkB, qkb, qk_g);
    attn_mfma_kernel<<<dim3(Q_DIM / BQ2, B_DIM), 256, 0, stream>>>(
        xt, ref, qk_g, wvh, bv, out);
  } else {
    // fallback: fp32 path
    const size_t QP_BYTES = (size_t)B_DIM * Q_DIM * C_DIM * 4;
    const size_t XTF_BYTES = (size_t)B_DIM * HW * C_DIM * 4;
    float* qp = nullptr;
    float* xtf = nullptr;
    if (ws_size >= QP_BYTES) qp = (float*)d_ws;
    if (ws_size >= QP_BYTES + XTF_BYTES) xtf = (float*)((char*)d_ws + QP_BYTES);

    if (xtf) {
      dim3 g((HW + 31) / 32, C_DIM / 32, B_DIM);
      transpose_kernel<<<g, dim3(32, 8), 0, stream>>>(x, xtf, C_DIM, HW);
    }
    if (qp) qp_kernel<<<B_DIM * Q_DIM / 16, 256, 0, stream>>>(q, wq, bq, qp);

    const float* src;
    int sB, sY, sX, sC;
    if (xtf) { src = xtf; sB = HW * C_DIM; sY = W_IMG * C_DIM; sX = C_DIM; sC = 1; }
    else     { src = x;   sB = C_DIM * HW; sY = W_IMG;         sX = 1;     sC = HW; }

    attn_fb_kernel<<<dim3(Q_DIM / BQ2, B_DIM), 256, 0, stream>>>(
        src, sB, sY, sX, sC, ref, qp, q, wq, bq, wk, wv, bv, out);
  }
}